// Round 8
// baseline (397.947 us; speedup 1.0000x reference)
//
#include <hip/hip_runtime.h>

// Problem dims
#define B_  32
#define N_  1024
#define E_  1024
#define H_  8
#define D_  128
#define MID_ 64
#define NT_  32        // n-tiles for score+pool (32 rows each)
#define TR_  32        // rows per tile
#define NS2_ 64        // n-splits for v2 pooling (16 rows each)

// Journal (counter-backed lessons):
//  R3: never scale occupancy by replaying the same stream (FETCH doubled).
//  R4: never scale same-destination atomic writers (WRITE 454 MB RMW).
//  R5: VGPR_Count=64 on a register-hungry kernel = spill to scratch.
//  R6: __launch_bounds__(X,4) forces the 64-VGPR tier -> spill; k_att
//      re-read PPpart 4x.
//  R7: plain bounds -> VGPR 72, WRITE = exactly ideal (32.8 MB). Scorepool
//      now: VALU 15% (~14us), HBM 1.1 TB/s -> ~75us of 92 is stall; 16
//      barriers/block each drain vmcnt(0) (HIP barrier semantics) killing
//      the prefetch. 1024-thr k_pre = 1 block/CU = 3 dispatch rounds.
//  => R8: halve barriers (8-row subtiles) + reg-neutral mid-outer reload;
//     fuse tail kernels; right-size k_pre blocks; 8-way P2 partials.

// ---------------------------------------------------------------------------
// k_pre: blocks [0,256): qkproj per (b,h), 256 thr (R3 coalesced form);
//        blocks [256, 256+2048): v2 pooling, 16-row splits, P2p[8] partials.
// ---------------------------------------------------------------------------
__global__ __launch_bounds__(256) void k_pre(
        const float* __restrict__ query, const float* __restrict__ Wq,
        const float* __restrict__ bq, const float* __restrict__ Wk,
        const float* __restrict__ bk, float* __restrict__ qk,
        float* __restrict__ qb,
        const float* __restrict__ value2, const int* __restrict__ mask,
        float* __restrict__ P2p)
{
    const int t = threadIdx.x;

    __shared__ __align__(16) float qsh[E_];   // staged query[b], 4 KB
    __shared__ float Qs[D_];
    __shared__ float red[4];
    __shared__ int rows[16];
    __shared__ int nrows;

    if (blockIdx.x < 256) {
        const int bh = blockIdx.x;
        const int b = bh >> 3, h = bh & 7;
        const int l = t & 63, w = t >> 6;       // 4 waves
        const int rg = l >> 4, cl = l & 15;     // 4 row-groups x 16 lanes

        ((float4*)qsh)[t] = ((const float4*)(query + (size_t)b * E_))[t];
        __syncthreads();

        // phase A: Q[d] = query[b]·Wq_row(h*D+d) + bq, 16 lanes per row
        const float4* qsh4 = (const float4*)qsh;
        float qbacc = 0.f;
        #pragma unroll 2
        for (int p = 0; p < 8; ++p) {
            const int d = p * 16 + w * 4 + rg;
            const int row = h * D_ + d;
            const float4* wr = (const float4*)(Wq + (size_t)row * E_);
            float acc = 0.f;
            #pragma unroll 4
            for (int i = 0; i < 16; ++i) {
                float4 wv = wr[cl + i * 16];
                float4 qv = qsh4[cl + i * 16];
                acc += wv.x * qv.x + wv.y * qv.y + wv.z * qv.z + wv.w * qv.w;
            }
            #pragma unroll
            for (int off = 8; off; off >>= 1) acc += __shfl_xor(acc, off);
            if (cl == 0) {
                float q = acc + bq[row];
                Qs[d] = q;
                qbacc += q * bk[row];
            }
        }
        #pragma unroll
        for (int off = 32; off; off >>= 1) qbacc += __shfl_down(qbacc, off);
        if (l == 0) red[w] = qbacc;
        __syncthreads();
        if (t == 0) qb[bh] = red[0] + red[1] + red[2] + red[3];

        // phase B: qk row, thread owns 4 e's (coalesced per d-iteration)
        const int e0 = t * 4;
        float4 a = make_float4(0.f, 0.f, 0.f, 0.f);
        const float* wkb = Wk + (size_t)(h * D_) * E_ + e0;
        #pragma unroll 8
        for (int d = 0; d < D_; ++d) {
            float Qd = Qs[d];
            float4 wv = *(const float4*)(wkb + (size_t)d * E_);
            a.x += Qd * wv.x; a.y += Qd * wv.y; a.z += Qd * wv.z; a.w += Qd * wv.w;
        }
        *(float4*)(qk + (size_t)bh * E_ + e0) = a;
    } else {
        // ---- v2 pooling: 16-row split; atomics into partial buffer ns&7
        const int idx = blockIdx.x - 256;
        const int b = idx & 31, ns = idx >> 5;    // ns in [0,64)
        const int e0 = t * 4;
        const int n0 = ns * 16;

        if (t == 0) nrows = 0;
        __syncthreads();
        if (t < 16) {
            if (mask[b * N_ + n0 + t]) {
                int i2 = atomicAdd(&nrows, 1);
                rows[i2] = t;
            }
        }
        __syncthreads();
        const int nr = nrows;

        float a0 = 0.f, a1 = 0.f, a2 = 0.f, a3 = 0.f;
        const float* vb = value2 + ((size_t)(b * N_ + n0)) * E_ + e0;
        for (int i = 0; i < nr; ++i) {
            float4 v = *(const float4*)(vb + (size_t)rows[i] * E_);
            a0 += v.x; a1 += v.y; a2 += v.z; a3 += v.w;
        }
        float* dst = P2p + ((size_t)(ns & 7) * B_ + b) * E_ + e0;
        atomicAdd(dst + 0, a0); atomicAdd(dst + 1, a1);
        atomicAdd(dst + 2, a2); atomicAdd(dst + 3, a3);
    }
}

// ---------------------------------------------------------------------------
// K2 single-pass score+pool v8: per (tile,b), 32-row tiles, 8-row subtiles.
//   4 iterations x 2 barriers (was 8 x 2); 8 KB of key loads issued per
//   burst; reg-neutral prefetch: reload kv[0..3] between the two outer
//   halves so next-subtile loads fly during outer(4..7) + loop edge.
//   Budget: qkr 32 + pacc 32 + kv 32 + temps ~ 119 VGPR (plain bounds).
// grid (NT_, B_) = 1024 blocks, 256 thr, ~1.3 KB LDS.
// ---------------------------------------------------------------------------
__global__ __launch_bounds__(256) void k_scorepool(
        const float* __restrict__ key, const float* __restrict__ qk,
        const float* __restrict__ qb, float* __restrict__ PPpart,
        float* __restrict__ ssum)
{
    const int tile = blockIdx.x, b = blockIdx.y;
    const int t = threadIdx.x;
    const int w = t >> 6, l = t & 63;

    __shared__ __align__(16) float part[4][8][8];   // [wave][row][h], 1 KB
    __shared__ __align__(16) float sfin[8][8];      // [row][h], 256 B

    const float scale = 0.08838834764831845f;  // 1/sqrt(128)
    const float* keyb = key + ((size_t)b * N_ + (size_t)tile * TR_) * E_;
    const float qbv = (t < 64) ? qb[b * 8 + (t & 7)] : 0.f;

    float4 qkr[8];
    #pragma unroll
    for (int h = 0; h < H_; ++h)
        qkr[h] = ((const float4*)(qk + (size_t)(b * 8 + h) * E_))[t];

    float4 pacc[8];
    #pragma unroll
    for (int h = 0; h < 8; ++h) pacc[h] = make_float4(0.f, 0.f, 0.f, 0.f);

    float ts = 0.f;

    float4 kv[8];
    #pragma unroll
    for (int r = 0; r < 8; ++r)
        kv[r] = ((const float4*)(keyb + (size_t)r * E_))[t];

#define OUTER_ROW(r)                                                        \
    {                                                                       \
        const float4 k4 = kv[r];                                            \
        const float4 sA = *(const float4*)&sfin[r][0];                      \
        const float4 sB = *(const float4*)&sfin[r][4];                      \
        pacc[0].x += sA.x * k4.x; pacc[0].y += sA.x * k4.y;                 \
        pacc[0].z += sA.x * k4.z; pacc[0].w += sA.x * k4.w;                 \
        pacc[1].x += sA.y * k4.x; pacc[1].y += sA.y * k4.y;                 \
        pacc[1].z += sA.y * k4.z; pacc[1].w += sA.y * k4.w;                 \
        pacc[2].x += sA.z * k4.x; pacc[2].y += sA.z * k4.y;                 \
        pacc[2].z += sA.z * k4.z; pacc[2].w += sA.z * k4.w;                 \
        pacc[3].x += sA.w * k4.x; pacc[3].y += sA.w * k4.y;                 \
        pacc[3].z += sA.w * k4.z; pacc[3].w += sA.w * k4.w;                 \
        pacc[4].x += sB.x * k4.x; pacc[4].y += sB.x * k4.y;                 \
        pacc[4].z += sB.x * k4.z; pacc[4].w += sB.x * k4.w;                 \
        pacc[5].x += sB.y * k4.x; pacc[5].y += sB.y * k4.y;                 \
        pacc[5].z += sB.y * k4.z; pacc[5].w += sB.y * k4.w;                 \
        pacc[6].x += sB.z * k4.x; pacc[6].y += sB.z * k4.y;                 \
        pacc[6].z += sB.z * k4.z; pacc[6].w += sB.z * k4.w;                 \
        pacc[7].x += sB.w * k4.x; pacc[7].y += sB.w * k4.y;                 \
        pacc[7].z += sB.w * k4.z; pacc[7].w += sB.w * k4.w;                 \
    }

    for (int st = 0; st < 4; ++st) {
        // --- dots: 8 rows x 8 heads, full-wave butterfly reduce
        #pragma unroll
        for (int r = 0; r < 8; ++r) {
            float p[8];
            #pragma unroll
            for (int h = 0; h < 8; ++h)
                p[h] = qkr[h].x * kv[r].x + qkr[h].y * kv[r].y
                     + qkr[h].z * kv[r].z + qkr[h].w * kv[r].w;
            #pragma unroll
            for (int off = 32; off; off >>= 1) {
                #pragma unroll
                for (int h = 0; h < 8; ++h)
                    p[h] += __shfl_xor(p[h], off);
            }
            if (l == 0) {
                *(float4*)&part[w][r][0] = make_float4(p[0], p[1], p[2], p[3]);
                *(float4*)&part[w][r][4] = make_float4(p[4], p[5], p[6], p[7]);
            }
        }
        __syncthreads();
        // --- finalize across 4 waves: 64 threads = (row, head)
        if (t < 64) {
            const int r = t >> 3, h = t & 7;
            float s = (part[0][r][h] + part[1][r][h]
                     + part[2][r][h] + part[3][r][h] + qbv) * scale;
            sfin[r][h] = s;
            ts += s;
        }
        __syncthreads();
        // --- outer half 1, then reload kv[0..3] (flies during half 2)
        OUTER_ROW(0) OUTER_ROW(1) OUTER_ROW(2) OUTER_ROW(3)
        if (st < 3) {
            #pragma unroll
            for (int r = 0; r < 4; ++r)
                kv[r] = ((const float4*)(keyb
                            + (size_t)((st + 1) * 8 + r) * E_))[t];
        }
        OUTER_ROW(4) OUTER_ROW(5) OUTER_ROW(6) OUTER_ROW(7)
        if (st < 3) {
            #pragma unroll
            for (int r = 4; r < 8; ++r)
                kv[r] = ((const float4*)(keyb
                            + (size_t)((st + 1) * 8 + r) * E_))[t];
        }
    }
#undef OUTER_ROW

    // --- ssum: t<64 hold per-(r,h) sums; fold r within wave 0, 8 atomics
    if (t < 64) {
        float v = ts;
        v += __shfl_down(v, 8);
        v += __shfl_down(v, 16);
        v += __shfl_down(v, 32);
        if (l < 8) atomicAdd(&ssum[b * 8 + l], v);
    }

    // --- PPpart: one plain float4 store per (h, e-chunk)
    #pragma unroll
    for (int h = 0; h < 8; ++h) {
        ((float4*)(PPpart
            + (((size_t)(b * H_ + h)) * NT_ + tile) * E_))[t] = pacc[h];
    }
}

// ---------------------------------------------------------------------------
// k_tail (fused k_red + k_att + k_final): per bh, 512 threads.
//  stage1: pooled = sum_tl PPpart[bh,tl,:] (2 halves); pool2 = sum P2p[8]
//  stage2: attA/attV[d] = pooled/pool2 · Wv_row(h*D+d), 8 waves x 16 d
//  stage3: k_final epilogue (hv, alphac, v2a, out)
// grid 256 blocks.
// ---------------------------------------------------------------------------
__global__ __launch_bounds__(512) void k_tail(
        const float* __restrict__ PPpart, const float* __restrict__ P2p,
        const float* __restrict__ ssumg, const int* __restrict__ mask,
        const float* __restrict__ Wv, const float* __restrict__ bv,
        const float* __restrict__ Wb, const float* __restrict__ bb,
        const float* __restrict__ Wl2, const float* __restrict__ bl2,
        const float* __restrict__ value1, float* __restrict__ out)
{
    const int bh = blockIdx.x, b = bh >> 3, h = bh & 7;
    const int t = threadIdx.x;
    const int l = t & 63, w = t >> 6;       // 8 waves
    const int rg = l >> 4, cl = l & 15;     // 4 row-groups x 16 lanes

    __shared__ __align__(16) float ph[2][E_];      // 8 KB tile-halves
    __shared__ __align__(16) float pooled[E_];
    __shared__ __align__(16) float pool2[E_];
    __shared__ float attA_s[D_];
    __shared__ float attV_s[D_];
    __shared__ float att[D_];
    __shared__ float hv[MID_];
    __shared__ float red2[2];
    __shared__ float cnt_s;

    // stage 1: reduce PPpart over NT tiles (two 16-tile halves)
    {
        const int c4 = t & 255, half = t >> 8;
        const float4* pp = (const float4*)(PPpart + (size_t)bh * NT_ * E_);
        float4 s = make_float4(0.f, 0.f, 0.f, 0.f);
        #pragma unroll 4
        for (int j = 0; j < 16; ++j) {
            float4 v = pp[(half * 16 + j) * 256 + c4];
            s.x += v.x; s.y += v.y; s.z += v.z; s.w += v.w;
        }
        ((float4*)&ph[half][0])[c4] = s;
    }
    __syncthreads();
    if (t < 256) {
        float4 p0 = ((const float4*)&ph[0][0])[t];
        float4 p1 = ((const float4*)&ph[1][0])[t];
        ((float4*)pooled)[t] = make_float4(p0.x + p1.x, p0.y + p1.y,
                                           p0.z + p1.z, p0.w + p1.w);
        float4 q = make_float4(0.f, 0.f, 0.f, 0.f);
        #pragma unroll
        for (int k2 = 0; k2 < 8; ++k2) {
            float4 v = ((const float4*)(P2p + ((size_t)k2 * B_ + b) * E_))[t];
            q.x += v.x; q.y += v.y; q.z += v.z; q.w += v.w;
        }
        ((float4*)pool2)[t] = q;
    }
    __syncthreads();

    // stage 2: Wv dots — 8 waves x 4 passes x 4 rg = 128 d
    const float4* pooled4 = (const float4*)pooled;
    const float4* pool24  = (const float4*)pool2;
    #pragma unroll
    for (int p = 0; p < 4; ++p) {
        const int d = p * 32 + w * 4 + rg;
        const float4* wvr = (const float4*)(Wv + (size_t)(h * D_ + d) * E_);
        float pA = 0.f, pV = 0.f;
        #pragma unroll 4
        for (int i = 0; i < 16; ++i) {
            float4 wv4 = wvr[cl + i * 16];
            float4 pa = pooled4[cl + i * 16];
            float4 pb = pool24[cl + i * 16];
            pA += wv4.x * pa.x + wv4.y * pa.y + wv4.z * pa.z + wv4.w * pa.w;
            pV += wv4.x * pb.x + wv4.y * pb.y + wv4.z * pb.z + wv4.w * pb.w;
        }
        #pragma unroll
        for (int off = 8; off; off >>= 1) {
            pA += __shfl_xor(pA, off);
            pV += __shfl_xor(pV, off);
        }
        if (cl == 0) { attA_s[d] = pA; attV_s[d] = pV; }
    }
    __syncthreads();

    // stage 3: epilogue (k_final logic on threads < 128)
    if (t < 128) {
        int ci = 0;
        #pragma unroll
        for (int i = 0; i < 8; ++i) ci += mask[b * N_ + t + i * 128];
        float cf = (float)ci;
        #pragma unroll
        for (int off = 32; off; off >>= 1) cf += __shfl_down(cf, off);
        if ((t & 63) == 0) red2[t >> 6] = cf;
        const float ss = ssumg[bh];
        att[t] = attA_s[t] + ss * bv[h * D_ + t];
    }
    __syncthreads();
    if (t == 0) cnt_s = red2[0] + red2[1];
    if (t < MID_) {
        float a = bb[t];
        #pragma unroll 4
        for (int d2 = 0; d2 < D_; ++d2) a += att[d2] * Wb[t * D_ + d2];
        hv[t] = fmaxf(a, 0.f);
    }
    __syncthreads();
    if (t < 128) {
        float z = bl2[t];
        #pragma unroll
        for (int m = 0; m < MID_; ++m) z += hv[m] * Wl2[t * MID_ + m];
        float alphac = 1.f / (1.f + expf(-z));
        const float bvd = bv[h * D_ + t];
        float v2a = attV_s[t] / cnt_s + bvd;
        out[(size_t)b * E_ + h * D_ + t] =
            value1[(size_t)b * E_ + h * D_ + t] * v2a * alphac;
    }
}

// ---------------------------------------------------------------------------
extern "C" void kernel_launch(void* const* d_in, const int* in_sizes, int n_in,
                              void* d_out, int out_size, void* d_ws, size_t ws_size,
                              hipStream_t stream)
{
    const float* query  = (const float*)d_in[0];
    const float* key    = (const float*)d_in[1];
    const int*   mask   = (const int*)d_in[2];
    const float* value1 = (const float*)d_in[3];
    const float* value2 = (const float*)d_in[4];
    const float* Wq  = (const float*)d_in[5];
    const float* bq  = (const float*)d_in[6];
    const float* Wk  = (const float*)d_in[7];
    const float* bk  = (const float*)d_in[8];
    const float* Wv  = (const float*)d_in[9];
    const float* bv  = (const float*)d_in[10];
    const float* Wb  = (const float*)d_in[11];
    const float* bb  = (const float*)d_in[12];
    // d_in[13] = Wl, d_in[14] = bl: eliminated (softmax over identical values = mask/cnt)
    const float* Wl2 = (const float*)d_in[15];
    const float* bl2 = (const float*)d_in[16];
    float* out = (float*)d_out;

    // workspace layout (bytes), total ~35 MB
    char* ws = (char*)d_ws;
    const size_t SZ_PPP = (size_t)B_ * H_ * NT_ * E_ * 4;     // PPpart: 32 MB
    const size_t SZ_P2P = (size_t)8 * B_ * E_ * 4;            // P2p: 1 MB
    const size_t OFF_P2P = SZ_PPP;
    const size_t OFF_SS  = OFF_P2P + SZ_P2P;                  // ssum: 1 KB
    const size_t OFF_QB  = OFF_SS + 1024;                     // qb: 1 KB
    const size_t OFF_QK  = OFF_QB + 1024;                     // qk: 1 MB
    float* PPpart = (float*)(ws);
    float* P2p  = (float*)(ws + OFF_P2P);
    float* ssum = (float*)(ws + OFF_SS);
    float* qb   = (float*)(ws + OFF_QB);
    float* qk   = (float*)(ws + OFF_QK);

    // zero the atomic-accumulated region (P2p + ssum); PPpart is fully
    // overwritten by plain stores. stream-ordered, capture-safe
    hipMemsetAsync(ws + OFF_P2P, 0, SZ_P2P + 1024, stream);

    hipLaunchKernelGGL(k_pre, dim3(256 + NS2_ * B_), dim3(256), 0, stream,
                       query, Wq, bq, Wk, bk, qk, qb, value2, mask, P2p);
    hipLaunchKernelGGL(k_scorepool, dim3(NT_, B_), dim3(256), 0, stream,
                       key, qk, qb, PPpart, ssum);
    hipLaunchKernelGGL(k_tail, dim3(B_ * H_), dim3(512), 0, stream,
                       PPpart, P2p, ssum, mask, Wv, bv, Wb, bb, Wl2, bl2,
                       value1, out);
}